// Round 10
// baseline (662.317 us; speedup 1.0000x reference)
//
#include <hip/hip_runtime.h>

#define NAGENT 8192
#define NCELL 36
#define HIDDEN 128
#define CSTRIDE 37    // tail LDS occ row stride (gcd(37,32)=1)
#define PWORDS 18     // 36 cells packed as 18 u32 (2 x u16)
#define NROWS 64      // 8x8 clamp grid: border rows absorb out-of-range points
#define NCHUNK 16
#define JCHUNK (NAGENT / NCHUNK)  // 512 js per block, 128 per wave

typedef float v2f __attribute__((ext_vector_type(2)));

// ---------------------------------------------------------------------------
// Fused kernel. Grid dim3(NCHUNK, 128) = 2048 blocks -> 8/CU x 4 waves =
// 32 waves/CU. Phase A = R8's histogram (best measured: k1 is LDS-atomic-
// ISSUE-bound, ~18cyc per wave-ds_add regardless of lanes/banks; R3/R7/R8
// all ~30.5us at 4096 issues/CU — R9's sort+skip regressed, reverted).
// Phase B: the LAST chunk-block per agent-group (flags arrival counter,
// no spinning -> scheduling-safe) reduces the 16 partials and does the
// 64-agent GEMM inline — removes the k2 dispatch + gap.
// Occupancy guards: LDS = 16K cnt + 2.4K occ + 4 = 18.8 KB -> 8 blocks/CU;
// __launch_bounds__(256,8) caps VGPR <= 64 so phase A keeps 8 waves/SIMD
// (tail reads occ straight from LDS and W from global/L1 to avoid a 36-reg
// occf blowing the cap; tail perf is irrelevant, 128 blocks total).
// Coherence: producer st -> __threadfence (device-scope release) ->
// __syncthreads -> atomicAdd(flag, device-scope); consumer observes 15 ->
// __threadfence (acquire/L1-inv) -> loads. (Guide §6 G16 pattern.)
// ---------------------------------------------------------------------------
__global__ __launch_bounds__(256, 8) void occ_fused_kernel(
    const float2* __restrict__ obs, const float* __restrict__ W,
    const float* __restrict__ bias, unsigned* __restrict__ partial,
    unsigned* __restrict__ flags, float* __restrict__ out) {
  __shared__ unsigned cnt[NROWS * 64];   // 16 KB
  __shared__ float occ[16 * CSTRIDE];    // 2.4 KB (tail only)
  __shared__ unsigned tail_old;
  const int tid  = threadIdx.x;
  const int lane = tid & 63;
  const int wv   = tid >> 6;
  const int gy   = blockIdx.y;

#pragma unroll
  for (int k = tid; k < NROWS * 64; k += 256) cnt[k] = 0u;
  __syncthreads();

  // ---- Phase A: histogram (identical to R8) ----
  const int agent = gy * 64 + lane;
  const float2 oi = obs[agent];
  const v2f two = {2.0f, 2.0f};
  const v2f cxy = {fmaf(oi.x, -2.0f, 3.0f), fmaf(oi.y, -2.0f, 3.0f)};
  unsigned* base = cnt + 9 * 64 + lane;  // +9 folds the [-1,6]^2 -> row offset

  const int jbeg = blockIdx.x * JCHUNK + wv * (JCHUNK / 4);
  const float4* jp = (const float4*)obs + (jbeg >> 1);

#pragma unroll 8
  for (int t = 0; t < JCHUNK / 8; ++t) {
    const float4 o2 = jp[t];  // wave-uniform addr -> broadcast load
    {
      const v2f p = {o2.x, o2.y};
      const v2f r = __builtin_elementwise_fma(p, two, cxy);  // v_pk_fma_f32
      const int ux = (int)__builtin_floorf(__builtin_amdgcn_fmed3f(r.x, -1.0f, 6.0f));
      const int uy = (int)__builtin_floorf(__builtin_amdgcn_fmed3f(r.y, -1.0f, 6.0f));
      atomicAdd(&base[(ux * 8 + uy) * 64], 1u);  // unconditional ds_add
    }
    {
      const v2f p = {o2.z, o2.w};
      const v2f r = __builtin_elementwise_fma(p, two, cxy);
      const int ux = (int)__builtin_floorf(__builtin_amdgcn_fmed3f(r.x, -1.0f, 6.0f));
      const int uy = (int)__builtin_floorf(__builtin_amdgcn_fmed3f(r.y, -1.0f, 6.0f));
      atomicAdd(&base[(ux * 8 + uy) * 64], 1u);
    }
  }
  __syncthreads();

  // harvest interior 6x6 rows -> 18 packed u16 words, layout [chunk][w][agent]
  unsigned* gbase = partial + (size_t)blockIdx.x * PWORDS * NAGENT +
                    (size_t)gy * 64;
  for (int k = tid; k < PWORDS * 64; k += 256) {
    const int w = k >> 6, l = k & 63;
    const int c0 = 2 * w, c1 = 2 * w + 1;
    const int r0 = (c0 / 6 + 1) * 8 + (c0 % 6 + 1);
    const int r1 = (c1 / 6 + 1) * 8 + (c1 % 6 + 1);
    gbase[(size_t)w * NAGENT + l] = cnt[r0 * 64 + l] | (cnt[r1 * 64 + l] << 16);
  }

  // ---- completion protocol ----
  __threadfence();            // release: my stores visible device-wide
  __syncthreads();            // all threads of this block have fenced
  if (tid == 0) tail_old = atomicAdd(&flags[gy], 1u);
  __syncthreads();
  if (tail_old != NCHUNK - 1) return;   // not last: done (no spinning)
  __threadfence();            // acquire: invalidate caches before reading

  // ---- Phase B (tail block only): reduce 16 partials + GEMM for 64 agents,
  //      processed in 4 quarters of 16 agents (occ LDS = 2.4 KB) ----
  for (int q = 0; q < 4; ++q) {
    const int agBase = gy * 64 + q * 16;
    for (int k = tid; k < 16 * PWORDS; k += 256) {
      const int a = k & 15, w = k >> 4;
      const unsigned* p = partial + (size_t)w * NAGENT + agBase + a;
      unsigned s = 0;
#pragma unroll
      for (int c = 0; c < NCHUNK; ++c) s += p[(size_t)c * PWORDS * NAGENT];
      float lo = (float)(s & 0xFFFFu);
      float hi = (float)(s >> 16);
      if (w == 10) hi -= 1.0f;  // cell 21: remove the always-counted self-pair
      occ[a * CSTRIDE + 2 * w]     = lo;
      occ[a * CSTRIDE + 2 * w + 1] = hi;
    }
    __syncthreads();

    const int a  = tid >> 4;
    const int hg = tid & 15;
    float acc[8];
#pragma unroll
    for (int k = 0; k < 8; ++k) acc[k] = bias[hg + 16 * k];

#pragma unroll
    for (int c4 = 0; c4 < 9; ++c4) {
#pragma unroll
      for (int k = 0; k < 8; ++k) {
        // W + h*36 floats = 144B stride -> float4-aligned; L1-hot (18 KB)
        const float4 w4 = *(const float4*)&W[(hg + 16 * k) * NCELL + c4 * 4];
        acc[k] = fmaf(occ[a * CSTRIDE + 4 * c4 + 0], w4.x, acc[k]);
        acc[k] = fmaf(occ[a * CSTRIDE + 4 * c4 + 1], w4.y, acc[k]);
        acc[k] = fmaf(occ[a * CSTRIDE + 4 * c4 + 2], w4.z, acc[k]);
        acc[k] = fmaf(occ[a * CSTRIDE + 4 * c4 + 3], w4.w, acc[k]);
      }
    }

    float* ob = out + (size_t)(agBase + a) * HIDDEN;
#pragma unroll
    for (int k = 0; k < 8; ++k) ob[hg + 16 * k] = acc[k];
    __syncthreads();  // occ reused next quarter
  }
}

extern "C" void kernel_launch(void* const* d_in, const int* in_sizes, int n_in,
                              void* d_out, int out_size, void* d_ws, size_t ws_size,
                              hipStream_t stream) {
  (void)in_sizes; (void)n_in; (void)out_size; (void)ws_size;
  const float2* obs = (const float2*)d_in[0];
  const float*  W   = (const float*)d_in[1];
  const float*  b   = (const float*)d_in[2];
  float* out = (float*)d_out;
  unsigned* partial = (unsigned*)d_ws;                    // 9.44 MB
  unsigned* flags   = partial + NCHUNK * PWORDS * NAGENT; // 128 u32

  hipMemsetAsync(flags, 0, 128 * sizeof(unsigned), stream);
  occ_fused_kernel<<<dim3(NCHUNK, 128), dim3(256), 0, stream>>>(
      obs, W, b, partial, flags, out);
}

// Round 11
// 98.198 us; speedup vs baseline: 6.7447x; 6.7447x over previous
//
#include <hip/hip_runtime.h>

#define NAGENT 8192
#define NCELL 36
#define HIDDEN 128
#define CSTRIDE 37    // k2 LDS occ row stride (gcd(37,32)=1)
#define PWORDS 18     // 36 cells packed as 18 u32 (2 x u16)
#define NCHUNK 16
#define JCHUNK (NAGENT / NCHUNK)  // 512 js per block, 128 per wave
#define HWORDS 32     // 8x8=64 clamp-grid cells packed 2-per-u32

typedef float v2f __attribute__((ext_vector_type(2)));

// ---------------------------------------------------------------------------
// k1: pairwise occupancy histogram. Grid dim3(NCHUNK, 128) = 2048 blocks.
// Block = 64 agents (lane = agent); 4 waves split the j-chunk (128 js each).
//
// R11: kill the LDS atomics. R3/R7/R8 pinned k1 at ~30.5us = 4096 wave-ds_add
// per CU x ~18cyc (issue cost invariant to lanes/banks/VALU). R10's fence-
// based fusion was catastrophic (device fences = per-block L2 flushes).
// Atomicity was only needed because 4 waves shared counter columns -> give
// each WAVE a private histogram: plain ds_read_b32 + v_add + ds_write_b32
// = 2 LDS issues (~11.6cyc, m134) vs 18cyc/ds_add. Per-wave DS ops are
// processed in order and columns are lane-private -> non-atomic RMW is safe.
// LDS: 4 waves x 32 words x 64 lanes x 4B = 32 KB -> 4 blocks/CU (16 waves,
// enough to saturate the LDS pipe: 16 x 256issues/9Kcyc chain = 0.45/cyc
// offered vs 0.17/cyc capacity). No __syncthreads until harvest.
// Grid coords shifted +1: r' = pj*2 + (4-2*oi), clamp fmed3[0,7] -> 8x8 grid,
// border rows absorb out-of-range; interior 6x6 harvested. Self-pair lands
// center (rounding drift flips only boundary pairs; absmax ~2 << thr 8, R8
// precedent), subtracted in k2 at cell 21.
// NOTE: relies on NaN-free obs (setup_inputs is randn).
// ---------------------------------------------------------------------------
__global__ __launch_bounds__(256) void occ_hist_kernel(
    const float2* __restrict__ obs, unsigned* __restrict__ partial) {
  __shared__ unsigned cnt[4 * HWORDS * 64];  // [wave][word][lane], 32 KB
  const int tid  = threadIdx.x;
  const int lane = tid & 63;
  const int wv   = tid >> 6;

  unsigned* hb = cnt + wv * (HWORDS * 64) + lane;  // wave-private, lane column
#pragma unroll
  for (int w = 0; w < HWORDS; ++w) hb[w * 64] = 0u;  // own region: no barrier

  const int agent = blockIdx.y * 64 + lane;
  const float2 oi = obs[agent];
  const v2f two = {2.0f, 2.0f};
  // +1 cell shift folded: r' = pj*2 + (4 - 2*oi) -> interior cells = 1..6
  const v2f cxy = {fmaf(oi.x, -2.0f, 4.0f), fmaf(oi.y, -2.0f, 4.0f)};

  const int jbeg = blockIdx.x * JCHUNK + wv * (JCHUNK / 4);
  const float4* jp = (const float4*)obs + (jbeg >> 1);

#pragma unroll 8
  for (int t = 0; t < JCHUNK / 8; ++t) {
    const float4 o2 = jp[t];  // wave-uniform addr -> broadcast load
    {
      const v2f p = {o2.x, o2.y};
      const v2f r = __builtin_elementwise_fma(p, two, cxy);  // v_pk_fma_f32
      const int ux = (int)__builtin_floorf(__builtin_amdgcn_fmed3f(r.x, 0.0f, 7.0f));
      const int uy = (int)__builtin_floorf(__builtin_amdgcn_fmed3f(r.y, 0.0f, 7.0f));
      const int row = ux * 8 + uy;                    // 0..63
      unsigned* p32 = hb + ((row >> 1) << 6);
      *p32 += 1u << ((row & 1) << 4);                 // ds_read+v_add+ds_write
    }
    {
      const v2f p = {o2.z, o2.w};
      const v2f r = __builtin_elementwise_fma(p, two, cxy);
      const int ux = (int)__builtin_floorf(__builtin_amdgcn_fmed3f(r.x, 0.0f, 7.0f));
      const int uy = (int)__builtin_floorf(__builtin_amdgcn_fmed3f(r.y, 0.0f, 7.0f));
      const int row = ux * 8 + uy;
      unsigned* p32 = hb + ((row >> 1) << 6);
      *p32 += 1u << ((row & 1) << 4);
    }
  }
  __syncthreads();

  // combine waves 1..3 into wave 0 (u32 adds of packed u16; block totals
  // <= 512 per half: no carry)
  for (int k = tid; k < HWORDS * 64; k += 256)
    cnt[k] += cnt[k + HWORDS * 64] + cnt[k + 2 * HWORDS * 64] + cnt[k + 3 * HWORDS * 64];
  __syncthreads();

  // harvest interior 6x6 -> 18 packed u16 words, layout [chunk][w][agent]
  unsigned* gbase = partial + (size_t)blockIdx.x * PWORDS * NAGENT +
                    (size_t)blockIdx.y * 64;
  for (int k = tid; k < PWORDS * 64; k += 256) {
    const int w = k >> 6, l = k & 63;
    const int c0 = 2 * w, c1 = 2 * w + 1;
    const int r0 = (c0 / 6 + 1) * 8 + (c0 % 6 + 1);   // grid row of cell c0
    const int r1 = (c1 / 6 + 1) * 8 + (c1 % 6 + 1);
    const unsigned v0 = (cnt[(r0 >> 1) * 64 + l] >> ((r0 & 1) << 4)) & 0xFFFFu;
    const unsigned v1 = (cnt[(r1 >> 1) * 64 + l] >> ((r1 & 1) << 4)) & 0xFFFFu;
    gbase[(size_t)w * NAGENT + l] = v0 | (v1 << 16);
  }
}

// ---------------------------------------------------------------------------
// k2: reduce NCHUNK packed partials (u32 adds; u16 halves can't carry since
// totals <= 8192), unpack to LDS, subtract the self-pair (cell 21 = word 10
// hi; always counted), then out = occ @ W^T + b. 512 blocks x 256 thr;
// 16 agents/block; thread = (agent, 8 h's). Reduce loop unrolled (16 loads
// in flight). W in LDS (144B rows: float4-aligned, <=2-way banks).
// ---------------------------------------------------------------------------
__global__ __launch_bounds__(256) void occ_gemm_kernel(
    const unsigned* __restrict__ partial, const float* __restrict__ W,
    const float* __restrict__ bias, float* __restrict__ out) {
  __shared__ float Wl[HIDDEN * NCELL];
  __shared__ float occ[16 * CSTRIDE];
  const int tid = threadIdx.x;

  const float4* W4 = (const float4*)W;
  float4* Wl4 = (float4*)Wl;
  for (int k = tid; k < HIDDEN * NCELL / 4; k += 256) Wl4[k] = W4[k];

  const int agBase = blockIdx.x * 16;
  for (int k = tid; k < 16 * PWORDS; k += 256) {
    const int a = k & 15, w = k >> 4;
    const unsigned* p = partial + (size_t)w * NAGENT + agBase + a;
    unsigned s = 0;
#pragma unroll
    for (int c = 0; c < NCHUNK; ++c) s += p[(size_t)c * PWORDS * NAGENT];
    float lo = (float)(s & 0xFFFFu);
    float hi = (float)(s >> 16);
    if (w == 10) hi -= 1.0f;  // cell 21: remove the always-counted self-pair
    occ[a * CSTRIDE + 2 * w]     = lo;
    occ[a * CSTRIDE + 2 * w + 1] = hi;
  }
  __syncthreads();

  const int a  = tid >> 4;
  const int hg = tid & 15;

  float occf[NCELL];
#pragma unroll
  for (int c = 0; c < NCELL; ++c) occf[c] = occ[a * CSTRIDE + c];

  float acc[8];
#pragma unroll
  for (int k = 0; k < 8; ++k) acc[k] = bias[hg + 16 * k];

#pragma unroll
  for (int c4 = 0; c4 < 9; ++c4) {
#pragma unroll
    for (int k = 0; k < 8; ++k) {
      const float4 w4 = *(const float4*)&Wl[(hg + 16 * k) * NCELL + c4 * 4];
      acc[k] = fmaf(occf[4 * c4 + 0], w4.x, acc[k]);
      acc[k] = fmaf(occf[4 * c4 + 1], w4.y, acc[k]);
      acc[k] = fmaf(occf[4 * c4 + 2], w4.z, acc[k]);
      acc[k] = fmaf(occf[4 * c4 + 3], w4.w, acc[k]);
    }
  }

  float* ob = out + (size_t)(agBase + a) * HIDDEN;
#pragma unroll
  for (int k = 0; k < 8; ++k) ob[hg + 16 * k] = acc[k];
}

extern "C" void kernel_launch(void* const* d_in, const int* in_sizes, int n_in,
                              void* d_out, int out_size, void* d_ws, size_t ws_size,
                              hipStream_t stream) {
  (void)in_sizes; (void)n_in; (void)out_size; (void)ws_size;
  const float2* obs = (const float2*)d_in[0];
  const float*  W   = (const float*)d_in[1];
  const float*  b   = (const float*)d_in[2];
  float* out = (float*)d_out;
  unsigned* partial = (unsigned*)d_ws;  // 16*18*8192*4 = 9.4 MB of workspace

  occ_hist_kernel<<<dim3(NCHUNK, 128), dim3(256), 0, stream>>>(obs, partial);
  occ_gemm_kernel<<<dim3(512), dim3(256), 0, stream>>>(partial, W, b, out);
}

// Round 12
// 89.025 us; speedup vs baseline: 7.4397x; 1.1030x over previous
//
#include <hip/hip_runtime.h>

#define NAGENT 8192
#define NCELL 36
#define HIDDEN 128
#define CSTRIDE 37    // k2 LDS occ row stride (gcd(37,32)=1)
#define PWORDS 18     // 36 cells packed as 18 u32 (2 x u16)
#define NROWS 64      // 8x8 clamp grid: border rows absorb out-of-range points
#define NCHUNK 16
#define JCHUNK (NAGENT / NCHUNK)  // 512 js per block, 128 per wave

// ---------------------------------------------------------------------------
// R12 = revert to R7 (best measured: 88.95 us, absmax 0.5).
// Final structure + the measured map of why each alternative lost:
//   k1 floor = LDS-atomic ISSUE throughput: 67M pairs / 64 lanes = 1.05M
//   wave-ds_add x ~18 cyc / 256 CU ~= 30.5 us, invariant across R3/R7/R8
//   (VALU 7..14 ops/pt, any bank layout, predicated or not).
//   - non-atomic ds_read+add+ds_write (R11): +9 us (dependent chain + half occ)
//   - sort + wave-batch bbox skip (R9): +26 us (overhead > skip upside @ randn)
//   - single-dispatch fusion, per-block device fences (R10): +570 us (L2 flush)
//   - branchless dummy-row always-add (R5): +2 us (atomic issues ~unchanged,
//     extra VALU)
// Residual wall time: 42.5 us harness 256MiB ws re-poison fill (timed stream,
// untouchable) + 30.5 us k1 + 2.5 us k2 + ~13 us graph node/gap overhead.
//
// k1: grid (NCHUNK,128) = 2048 blocks -> 8/CU x 4 waves = 32 waves/CU.
// lane = agent, 4 waves split the j-chunk (128 js each, wave-uniform global
// float4 broadcast loads). Per point: 2 sub + 2 fma + 2 cvt_flr + 2 med3 +
// 2 addr + 1 ds_add into an 8x8 clamp grid (border rows absorb out-of-range;
// interior 6x6 harvested). fmaf(xj-xi, 2, 3) is BIT-EXACT vs the reference
// ((oj-oi)/0.5 + 3): 2*dx exact, single rounding -> boundary classification
// matches numpy; self-pair (dx=0) lands exactly at row (4,4) = cell 21,
// subtracted in k2. Counters col-major cnt[row*64+lane]: bank = lane%32 ->
// 2-way = free (m136). NaN-free obs assumed (setup_inputs is randn).
// ---------------------------------------------------------------------------
__global__ __launch_bounds__(256) void occ_hist_kernel(
    const float2* __restrict__ obs, unsigned* __restrict__ partial) {
  __shared__ unsigned cnt[NROWS * 64];  // 16 KB -> 8 blocks/CU
  const int tid  = threadIdx.x;
  const int lane = tid & 63;
  const int wv   = tid >> 6;

#pragma unroll
  for (int k = tid; k < NROWS * 64; k += 256) cnt[k] = 0u;
  __syncthreads();

  const int agent = blockIdx.y * 64 + lane;
  const float2 oi = obs[agent];
  const float xi = oi.x, yi = oi.y;
  // row(v) for v = ux*8+uy, ux,uy in [-1,6] -> v in [-9,54]; +9 folded here:
  unsigned* base = cnt + 9 * 64 + lane;

  const int jbeg = blockIdx.x * JCHUNK + wv * (JCHUNK / 4);
  const float4* jp = (const float4*)obs + (jbeg >> 1);

#pragma unroll 8
  for (int t = 0; t < JCHUNK / 8; ++t) {
    const float4 o2 = jp[t];  // wave-uniform addr -> broadcast load (vmcnt)
    {
      const float rx = fmaf(o2.x - xi, 2.0f, 3.0f);   // bit-exact vs ref
      const float ry = fmaf(o2.y - yi, 2.0f, 3.0f);
      int ux = (int)__builtin_floorf(rx);             // v_cvt_flr_i32_f32
      int uy = (int)__builtin_floorf(ry);
      ux = min(max(ux, -1), 6);                       // v_med3_i32
      uy = min(max(uy, -1), 6);
      atomicAdd(&base[(ux * 8 + uy) * 64], 1u);       // unconditional ds_add
    }
    {
      const float rx = fmaf(o2.z - xi, 2.0f, 3.0f);
      const float ry = fmaf(o2.w - yi, 2.0f, 3.0f);
      int ux = (int)__builtin_floorf(rx);
      int uy = (int)__builtin_floorf(ry);
      ux = min(max(ux, -1), 6);
      uy = min(max(uy, -1), 6);
      atomicAdd(&base[(ux * 8 + uy) * 64], 1u);
    }
  }
  __syncthreads();

  // harvest interior 6x6 rows -> 18 packed u16 words (per-chunk counts<=513),
  // layout [chunk][w][agent]; LDS reads 2-way banks, stores coalesced 256B.
  unsigned* gbase = partial + (size_t)blockIdx.x * PWORDS * NAGENT +
                    (size_t)blockIdx.y * 64;
  for (int k = tid; k < PWORDS * 64; k += 256) {
    const int w = k >> 6, l = k & 63;
    const int c0 = 2 * w, c1 = 2 * w + 1;
    const int r0 = (c0 / 6 + 1) * 8 + (c0 % 6 + 1);
    const int r1 = (c1 / 6 + 1) * 8 + (c1 % 6 + 1);
    gbase[(size_t)w * NAGENT + l] = cnt[r0 * 64 + l] | (cnt[r1 * 64 + l] << 16);
  }
}

// ---------------------------------------------------------------------------
// k2: reduce NCHUNK packed partials (u32 adds; u16 halves can't carry since
// totals <= 8192), unpack to LDS, subtract the self-pair (cell 21 = word 10
// hi; always >= 1 since the self j is always counted), then occ @ W^T + b.
// 512 blocks x 256 thr; 16 agents/block; thread = (agent, 8 h's).
// Reduce loop compile-time unrolled (16 loads in flight, ~9.4 MB coalesced).
// W in LDS (144B rows: float4-aligned, <=2-way banks).
// ---------------------------------------------------------------------------
__global__ __launch_bounds__(256) void occ_gemm_kernel(
    const unsigned* __restrict__ partial, const float* __restrict__ W,
    const float* __restrict__ bias, float* __restrict__ out) {
  __shared__ float Wl[HIDDEN * NCELL];
  __shared__ float occ[16 * CSTRIDE];
  const int tid = threadIdx.x;

  const float4* W4 = (const float4*)W;
  float4* Wl4 = (float4*)Wl;
  for (int k = tid; k < HIDDEN * NCELL / 4; k += 256) Wl4[k] = W4[k];

  const int agBase = blockIdx.x * 16;
  for (int k = tid; k < 16 * PWORDS; k += 256) {
    const int a = k & 15, w = k >> 4;
    const unsigned* p = partial + (size_t)w * NAGENT + agBase + a;
    unsigned s = 0;
#pragma unroll
    for (int c = 0; c < NCHUNK; ++c) s += p[(size_t)c * PWORDS * NAGENT];
    float lo = (float)(s & 0xFFFFu);
    float hi = (float)(s >> 16);
    if (w == 10) hi -= 1.0f;  // cell 21: remove the always-counted self-pair
    occ[a * CSTRIDE + 2 * w]     = lo;
    occ[a * CSTRIDE + 2 * w + 1] = hi;
  }
  __syncthreads();

  const int a  = tid >> 4;
  const int hg = tid & 15;

  float occf[NCELL];
#pragma unroll
  for (int c = 0; c < NCELL; ++c) occf[c] = occ[a * CSTRIDE + c];

  float acc[8];
#pragma unroll
  for (int k = 0; k < 8; ++k) acc[k] = bias[hg + 16 * k];

#pragma unroll
  for (int c4 = 0; c4 < 9; ++c4) {
#pragma unroll
    for (int k = 0; k < 8; ++k) {
      const float4 w4 = *(const float4*)&Wl[(hg + 16 * k) * NCELL + c4 * 4];
      acc[k] = fmaf(occf[4 * c4 + 0], w4.x, acc[k]);
      acc[k] = fmaf(occf[4 * c4 + 1], w4.y, acc[k]);
      acc[k] = fmaf(occf[4 * c4 + 2], w4.z, acc[k]);
      acc[k] = fmaf(occf[4 * c4 + 3], w4.w, acc[k]);
    }
  }

  float* ob = out + (size_t)(agBase + a) * HIDDEN;
#pragma unroll
  for (int k = 0; k < 8; ++k) ob[hg + 16 * k] = acc[k];
}

extern "C" void kernel_launch(void* const* d_in, const int* in_sizes, int n_in,
                              void* d_out, int out_size, void* d_ws, size_t ws_size,
                              hipStream_t stream) {
  (void)in_sizes; (void)n_in; (void)out_size; (void)ws_size;
  const float2* obs = (const float2*)d_in[0];
  const float*  W   = (const float*)d_in[1];
  const float*  b   = (const float*)d_in[2];
  float* out = (float*)d_out;
  unsigned* partial = (unsigned*)d_ws;  // 16*18*8192*4 = 9.4 MB of workspace

  occ_hist_kernel<<<dim3(NCHUNK, 128), dim3(256), 0, stream>>>(obs, partial);
  occ_gemm_kernel<<<dim3(512), dim3(256), 0, stream>>>(partial, W, b, out);
}